// Round 9
// baseline (169.432 us; speedup 1.0000x reference)
//
#include <hip/hip_runtime.h>
#include <cstdint>
#include <cstddef>

typedef __attribute__((ext_vector_type(8))) short short8;
typedef __attribute__((ext_vector_type(4))) float floatx4;
typedef __attribute__((ext_vector_type(4))) unsigned short ushort4v;

#define NB 2
#define NPIX 2304
#define TBL 9025
#define TBLP 9032                      // padded to multiple of 8
#define L2E 1.4426950408889634f
#define QSCALE 0.17677669529663689f    // 1/sqrt(32)

__device__ __forceinline__ float b2f(unsigned short u) {
  union { unsigned int i; float f; } v; v.i = ((unsigned int)u) << 16; return v.f;
}
__device__ __forceinline__ unsigned short f2b(float f) {
  union { float f; unsigned int i; } v; v.f = f;
  return (unsigned short)((v.i + 0x7fffu + ((v.i >> 16) & 1u)) >> 16);
}
__device__ __forceinline__ unsigned short f2b_fast(float f) {   // round-half-up
  union { float f; unsigned int i; } v; v.f = f;
  return (unsigned short)((v.i + 0x8000u) >> 16);
}

// ---------------------------------------------------------------------------
// Prep: fp32->bf16 weight conversion + per-head fp32 bias table (x log2e).
// ---------------------------------------------------------------------------
__global__ __launch_bounds__(256) void prep_k(
    const float* __restrict__ gamma, const float* __restrict__ wqkv,
    const float* __restrict__ wout, const float* __restrict__ table,
    unsigned short* __restrict__ gb, unsigned short* __restrict__ qb,
    unsigned short* __restrict__ wb, float* __restrict__ tbf)
{
  int i = blockIdx.x * 256 + threadIdx.x;
  if (i < 65536)  gb[i] = f2b(gamma[i]);
  if (i < 196608) qb[i] = f2b(wqkv[i]);
  if (i < 65536)  wb[i] = f2b(wout[i]);
  if (i < TBL * 8) {
    int e = i >> 3, h = i & 7;
    tbf[(size_t)h * TBLP + e] = table[i] * L2E;
  }
}

// ---------------------------------------------------------------------------
// 64x64-tile bf16 MFMA GEMM, K=256, N=2304 per batch. A pre-converted bf16.
// MODE 0: norm = gamma @ x^2   -> xn = x*rsqrt(beta+norm), store xn^T [b][n][c]
// MODE 1: qkv  = w_qkv @ xn    -> q(*QSCALE*L2E)/k [b][h][n][32]; v TRANSPOSED [b][h][32][n]
// MODE 2: out  = w_out @ res^T + b_out -> FP32 [b][c][n]
// ---------------------------------------------------------------------------
template<int MODE>
__global__ __launch_bounds__(256) void gemm_k(
    const unsigned short* __restrict__ A,   // [M][256] bf16 weights
    const void* __restrict__ Bv,            // MODE0: fp32 x [b][256][2304]; else bf16 [b][2304][256]
    const float* __restrict__ vec,          // beta (MODE0) / b_out (MODE2)
    unsigned short* __restrict__ o0,
    unsigned short* __restrict__ o1,
    unsigned short* __restrict__ o2,
    float* __restrict__ of)
{
  __shared__ unsigned short Al[64][40];
  __shared__ unsigned short Bl[64][40];
  const float* __restrict__ X = (const float*)Bv;                    // MODE 0
  const unsigned short* __restrict__ Bw = (const unsigned short*)Bv; // MODE 1/2

  const int n0 = blockIdx.x * 64;
  const int m0 = blockIdx.y * 64;
  const int b  = blockIdx.z;
  const int tid = threadIdx.x;
  const int wave = tid >> 6, lane = tid & 63;
  const int wm = wave >> 1, wn = wave & 1;
  const int lm = lane & 15, quad = lane >> 4;

  floatx4 acc[2][2] = {};

  for (int k0 = 0; k0 < 256; k0 += 32) {
    __syncthreads();
    { // stage A tile [64][32] (bf16 copy)
      int ml = tid >> 2, ko = (tid & 3) * 8;
      *(short8*)&Al[ml][ko] = *(const short8*)&A[(size_t)(m0 + ml) * 256 + k0 + ko];
    }
    if (MODE == 0) { // B = x^2 (fp32 src), transpose-stage from [c][n]
      int kk = tid >> 3, n8 = (tid & 7) * 8;
      const float* xr = &X[((size_t)(b * 256 + k0 + kk)) * NPIX + n0 + n8];
      float4 x0 = *(const float4*)xr;
      float4 x1 = *(const float4*)(xr + 4);
      Bl[n8 + 0][kk] = f2b(x0.x * x0.x);
      Bl[n8 + 1][kk] = f2b(x0.y * x0.y);
      Bl[n8 + 2][kk] = f2b(x0.z * x0.z);
      Bl[n8 + 3][kk] = f2b(x0.w * x0.w);
      Bl[n8 + 4][kk] = f2b(x1.x * x1.x);
      Bl[n8 + 5][kk] = f2b(x1.y * x1.y);
      Bl[n8 + 6][kk] = f2b(x1.z * x1.z);
      Bl[n8 + 7][kk] = f2b(x1.w * x1.w);
    } else {
      int nl = tid >> 2, ko = (tid & 3) * 8;
      short8 bv = *(const short8*)&Bw[((size_t)b * NPIX + n0 + nl) * 256 + k0 + ko];
      *(short8*)&Bl[nl][ko] = bv;
    }
    __syncthreads();
    short8 af[2], bfr[2];
    #pragma unroll
    for (int tm = 0; tm < 2; ++tm)
      af[tm] = *(const short8*)&Al[wm*32 + tm*16 + lm][quad*8];
    #pragma unroll
    for (int tn = 0; tn < 2; ++tn)
      bfr[tn] = *(const short8*)&Bl[wn*32 + tn*16 + lm][quad*8];
    #pragma unroll
    for (int tm = 0; tm < 2; ++tm)
      #pragma unroll
      for (int tn = 0; tn < 2; ++tn)
        acc[tm][tn] = __builtin_amdgcn_mfma_f32_16x16x32_bf16(af[tm], bfr[tn], acc[tm][tn], 0, 0, 0);
  }

  // epilogue: D[row][col], row = quad*4+reg (+tile), col = lane&15 (+tile)
  #pragma unroll
  for (int tm = 0; tm < 2; ++tm) {
    const int rbase = m0 + wm*32 + tm*16 + quad*4;
    #pragma unroll
    for (int tn = 0; tn < 2; ++tn) {
      const int col = n0 + wn*32 + tn*16 + lm;
      floatx4 a4 = acc[tm][tn];
      if (MODE == 0) {
        ushort4v pk;
        #pragma unroll
        for (int r = 0; r < 4; ++r) {
          int d = rbase + r;
          float xv = X[((size_t)(b * 256 + d)) * NPIX + col];
          pk[r] = f2b(xv * rsqrtf(vec[d] + a4[r]));
        }
        *(ushort4v*)&o0[((size_t)(b * NPIX + col)) * 256 + rbase] = pk;
      } else if (MODE == 1) {
        const int part = rbase >> 8, h = (rbase >> 5) & 7, dd = rbase & 31;
        if (part == 2) {           // V transposed: [b][h][d][n]
          #pragma unroll
          for (int r = 0; r < 4; ++r)
            o2[(((size_t)(b * 8 + h)) * 32 + dd + r) * NPIX + col] = f2b(a4[r]);
        } else {
          unsigned short* dst = part == 0 ? o0 : o1;
          const float sc = (part == 0) ? (QSCALE * L2E) : 1.0f;
          ushort4v pk;
          #pragma unroll
          for (int r = 0; r < 4; ++r) pk[r] = f2b(a4[r] * sc);
          *(ushort4v*)&dst[(((size_t)(b * 8 + h)) * NPIX + col) * 32 + dd] = pk;
        }
      } else {
        #pragma unroll
        for (int r = 0; r < 4; ++r) {
          int c = rbase + r;
          of[((size_t)(b * 256 + c)) * NPIX + col] = a4[r] + vec[c];
        }
      }
    }
  }
}

// ---------------------------------------------------------------------------
// Barrier-free MFMA flash attention (transposed orientation).
// Block = 256 thr = 4 waves, 16 queries/wave, grid (36 qtiles, 16 bh).
// Inner loop: S^T = K*Q^T (K frags = direct global loads), bias from fp32 LDS
// table (1 ds_read_b32 + 1 v_add each), p = v_exp_f32 via
// __builtin_amdgcn_exp2f, P packed half-up to LDS, O^T += V^T*P^T with V
// frags direct from pre-transposed V.
// ---------------------------------------------------------------------------
__global__ __launch_bounds__(256) void attn_k(
    const unsigned short* __restrict__ qg, const unsigned short* __restrict__ kg,
    const unsigned short* __restrict__ vt, const float* __restrict__ tabf_g,
    unsigned short* __restrict__ ob)
{
  __shared__ __align__(16) float tabf[TBLP];             // 36.1 KB fp32 bias (x L2E)
  __shared__ __align__(16) unsigned short Pl[4][16][72]; // 9.2 KB, per-wave

  const int tid = threadIdx.x;
  const int w = tid >> 6, lane = tid & 63;
  const int lm = lane & 15, quad = lane >> 4;
  const int q0 = blockIdx.x * 64;
  const int bh = blockIdx.y;
  const size_t base = (size_t)bh * NPIX * 32;

  { // stage per-head fp32 bias slice
    const float* src = tabf_g + (size_t)(bh & 7) * TBLP;
    for (int e = tid * 4; e < TBLP; e += 1024)
      *(float4*)&tabf[e] = *(const float4*)&src[e];
  }
  __syncthreads();   // only barrier in the kernel

  // Q fragment: B-operand for S^T (n=lm=q, k=quad*8+j=d); pre-scaled QSCALE*L2E
  const int q = q0 + w * 16 + lm;
  const short8 qfrag = *(const short8*)&qg[base + (size_t)q * 32 + quad * 8];

  // bias row base for this lane's query
  const int hi = (q * 43691) >> 21;                  // q / 48
  const int rb = (hi + 47) * 95 + (q - hi * 48) + 47;

  float lsum = 0.f;
  floatx4 o[2] = {};

  for (int t = 0; t < 36; ++t) {
    const int j0 = t * 64;
    // S^T[key][q]: rows = keys (quad*4+r per kt), cols = queries (lm)
    floatx4 s4[4];
    #pragma unroll
    for (int kt = 0; kt < 4; ++kt) {
      short8 kf = *(const short8*)&kg[base + (size_t)(j0 + kt * 16 + lm) * 32 + quad * 8];
      floatx4 z = {};
      s4[kt] = __builtin_amdgcn_mfma_f32_16x16x32_bf16(kf, qfrag, z, 0, 0, 0);
    }
    // + bias, exp2, accumulate l, pack P
    #pragma unroll
    for (int kt = 0; kt < 4; ++kt) {
      const int key0 = j0 + kt * 16 + quad * 4;      // 4-aligned: same 48-row for r=0..3
      const int hj = (key0 * 43691) >> 21;           // key0 / 48
      const int ib = rb - key0 - hj * 47;            // bias idx for r=0, decreasing in r
      ushort4v pk;
      #pragma unroll
      for (int r = 0; r < 4; ++r) {
        float p = __builtin_amdgcn_exp2f(s4[kt][r] + tabf[ib - r]);
        lsum += p;
        pk[r] = f2b_fast(p);
      }
      *(ushort4v*)&Pl[w][lm][kt * 16 + quad * 4] = pk;   // P[q][key] layout
    }
    __asm__ volatile("s_waitcnt lgkmcnt(0)" ::: "memory"); // wave-local DS order
    // O^T[d][q] += V^T[d][key] * P^T[key][q]
    #pragma unroll
    for (int c = 0; c < 2; ++c) {
      short8 pf = *(const short8*)&Pl[w][lm][c * 32 + quad * 8];
      #pragma unroll
      for (int dt = 0; dt < 2; ++dt) {
        short8 vf = *(const short8*)&vt[base + (size_t)(dt * 16 + lm) * NPIX + j0 + c * 32 + quad * 8];
        o[dt] = __builtin_amdgcn_mfma_f32_16x16x32_bf16(vf, pf, o[dt], 0, 0, 0);
      }
    }
  }

  // reduce l across the 4 quads holding the same query
  lsum += __shfl_xor(lsum, 16, 64);
  lsum += __shfl_xor(lsum, 32, 64);
  const float inv = 1.f / lsum;

  // store O[q][d] bf16: lane holds d = dt*16 + quad*4 + r at its query q
  #pragma unroll
  for (int dt = 0; dt < 2; ++dt) {
    ushort4v pk;
    #pragma unroll
    for (int r = 0; r < 4; ++r) pk[r] = f2b(o[dt][r] * inv);
    *(ushort4v*)&ob[base + (size_t)q * 32 + dt * 16 + quad * 4] = pk;
  }
}

// ---------------------------------------------------------------------------
extern "C" void kernel_launch(void* const* d_in, const int* in_sizes, int n_in,
                              void* d_out, int out_size, void* d_ws, size_t ws_size,
                              hipStream_t stream) {
  const float* x     = (const float*)d_in[0];
  const float* beta  = (const float*)d_in[1];
  const float* gamma = (const float*)d_in[2];
  const float* wqkv  = (const float*)d_in[3];
  const float* wout  = (const float*)d_in[4];
  const float* bout  = (const float*)d_in[5];
  const float* table = (const float*)d_in[6];
  float* out = (float*)d_out;   // reference output dtype is float32

  unsigned short* ws = (unsigned short*)d_ws;
  const size_t NE = (size_t)NB * NPIX * 256;   // 1,179,648 elems per tensor
  unsigned short* xn_t  = ws;                  // [b][n][256] bf16
  unsigned short* qbuf  = ws + NE;             // [b][h][n][32] bf16, *QSCALE*L2E
  unsigned short* kbuf  = ws + 2 * NE;         // [b][h][n][32]
  unsigned short* vtbuf = ws + 3 * NE;         // [b][h][32][n]  (transposed)
  unsigned short* obuf  = ws + 4 * NE;         // [b][h][n][32] == res[b][n2][e]
  // bf16 weights: gamma/wqkv alias obuf (dead before attn writes it)
  unsigned short* gam_b = obuf;                // 65536
  unsigned short* qkv_b = obuf + 65536;        // 196608 (fits in NE)
  unsigned short* out_b = ws + 5 * NE;         // 65536 (live through gemm2)
  float* tab_f = (float*)(ws + 5 * NE + 65536); // 8*TBLP fp32 (live through attn)

  prep_k<<<768, 256, 0, stream>>>(gamma, wqkv, wout, table, gam_b, qkv_b, out_b, tab_f);
  gemm_k<0><<<dim3(36, 4, 2), 256, 0, stream>>>(gam_b, x, beta, xn_t, nullptr, nullptr, nullptr);
  gemm_k<1><<<dim3(36, 12, 2), 256, 0, stream>>>(qkv_b, xn_t, nullptr, qbuf, kbuf, vtbuf, nullptr);
  attn_k<<<dim3(36, 16), 256, 0, stream>>>(qbuf, kbuf, vtbuf, tab_f, obuf);
  gemm_k<2><<<dim3(36, 4, 2), 256, 0, stream>>>(out_b, obuf, bout, nullptr, nullptr, nullptr, out);
}

// Round 10
// 169.207 us; speedup vs baseline: 1.0013x; 1.0013x over previous
//
#include <hip/hip_runtime.h>
#include <cstdint>
#include <cstddef>

typedef __attribute__((ext_vector_type(8))) short short8;
typedef __attribute__((ext_vector_type(4))) float floatx4;
typedef __attribute__((ext_vector_type(4))) unsigned short ushort4v;

#define NB 2
#define NPIX 2304
#define TBL 9025
#define TBLP 9032                      // padded to multiple of 8
#define L2E 1.4426950408889634f
#define QSCALE 0.17677669529663689f    // 1/sqrt(32)

__device__ __forceinline__ float b2f(unsigned short u) {
  union { unsigned int i; float f; } v; v.i = ((unsigned int)u) << 16; return v.f;
}
__device__ __forceinline__ unsigned short f2b(float f) {
  union { float f; unsigned int i; } v; v.f = f;
  return (unsigned short)((v.i + 0x7fffu + ((v.i >> 16) & 1u)) >> 16);
}
__device__ __forceinline__ unsigned short f2b_fast(float f) {   // round-half-up
  union { float f; unsigned int i; } v; v.f = f;
  return (unsigned short)((v.i + 0x8000u) >> 16);
}

// ---------------------------------------------------------------------------
// Prep: fp32->bf16 weight conversion + per-head fp32 bias table (x log2e).
// ---------------------------------------------------------------------------
__global__ __launch_bounds__(256) void prep_k(
    const float* __restrict__ gamma, const float* __restrict__ wqkv,
    const float* __restrict__ wout, const float* __restrict__ table,
    unsigned short* __restrict__ gb, unsigned short* __restrict__ qb,
    unsigned short* __restrict__ wb, float* __restrict__ tbf)
{
  int i = blockIdx.x * 256 + threadIdx.x;
  if (i < 65536)  gb[i] = f2b(gamma[i]);
  if (i < 196608) qb[i] = f2b(wqkv[i]);
  if (i < 65536)  wb[i] = f2b(wout[i]);
  if (i < TBL * 8) {
    int e = i >> 3, h = i & 7;
    tbf[(size_t)h * TBLP + e] = table[i] * L2E;
  }
}

// ---------------------------------------------------------------------------
// 64x64-tile bf16 MFMA GEMM, K=256, N=2304 per batch. A pre-converted bf16.
// MODE 0: norm = gamma @ x^2   -> xn = x*rsqrt(beta+norm), store xn^T [b][n][c]
// MODE 1: qkv  = w_qkv @ xn    -> q(*QSCALE*L2E)/k [b][h][n][32]; v TRANSPOSED [b][h][32][n]
// MODE 2: out  = w_out @ res^T + b_out -> FP32 [b][c][n]
// ---------------------------------------------------------------------------
template<int MODE>
__global__ __launch_bounds__(256) void gemm_k(
    const unsigned short* __restrict__ A,   // [M][256] bf16 weights
    const void* __restrict__ Bv,            // MODE0: fp32 x [b][256][2304]; else bf16 [b][2304][256]
    const float* __restrict__ vec,          // beta (MODE0) / b_out (MODE2)
    unsigned short* __restrict__ o0,
    unsigned short* __restrict__ o1,
    unsigned short* __restrict__ o2,
    float* __restrict__ of)
{
  __shared__ unsigned short Al[64][40];
  __shared__ unsigned short Bl[64][40];
  const float* __restrict__ X = (const float*)Bv;                    // MODE 0
  const unsigned short* __restrict__ Bw = (const unsigned short*)Bv; // MODE 1/2

  const int n0 = blockIdx.x * 64;
  const int m0 = blockIdx.y * 64;
  const int b  = blockIdx.z;
  const int tid = threadIdx.x;
  const int wave = tid >> 6, lane = tid & 63;
  const int wm = wave >> 1, wn = wave & 1;
  const int lm = lane & 15, quad = lane >> 4;

  floatx4 acc[2][2] = {};

  for (int k0 = 0; k0 < 256; k0 += 32) {
    __syncthreads();
    { // stage A tile [64][32] (bf16 copy)
      int ml = tid >> 2, ko = (tid & 3) * 8;
      *(short8*)&Al[ml][ko] = *(const short8*)&A[(size_t)(m0 + ml) * 256 + k0 + ko];
    }
    if (MODE == 0) { // B = x^2 (fp32 src), transpose-stage from [c][n]
      int kk = tid >> 3, n8 = (tid & 7) * 8;
      const float* xr = &X[((size_t)(b * 256 + k0 + kk)) * NPIX + n0 + n8];
      float4 x0 = *(const float4*)xr;
      float4 x1 = *(const float4*)(xr + 4);
      Bl[n8 + 0][kk] = f2b(x0.x * x0.x);
      Bl[n8 + 1][kk] = f2b(x0.y * x0.y);
      Bl[n8 + 2][kk] = f2b(x0.z * x0.z);
      Bl[n8 + 3][kk] = f2b(x0.w * x0.w);
      Bl[n8 + 4][kk] = f2b(x1.x * x1.x);
      Bl[n8 + 5][kk] = f2b(x1.y * x1.y);
      Bl[n8 + 6][kk] = f2b(x1.z * x1.z);
      Bl[n8 + 7][kk] = f2b(x1.w * x1.w);
    } else {
      int nl = tid >> 2, ko = (tid & 3) * 8;
      short8 bv = *(const short8*)&Bw[((size_t)b * NPIX + n0 + nl) * 256 + k0 + ko];
      *(short8*)&Bl[nl][ko] = bv;
    }
    __syncthreads();
    short8 af[2], bfr[2];
    #pragma unroll
    for (int tm = 0; tm < 2; ++tm)
      af[tm] = *(const short8*)&Al[wm*32 + tm*16 + lm][quad*8];
    #pragma unroll
    for (int tn = 0; tn < 2; ++tn)
      bfr[tn] = *(const short8*)&Bl[wn*32 + tn*16 + lm][quad*8];
    #pragma unroll
    for (int tm = 0; tm < 2; ++tm)
      #pragma unroll
      for (int tn = 0; tn < 2; ++tn)
        acc[tm][tn] = __builtin_amdgcn_mfma_f32_16x16x32_bf16(af[tm], bfr[tn], acc[tm][tn], 0, 0, 0);
  }

  // epilogue: D[row][col], row = quad*4+reg (+tile), col = lane&15 (+tile)
  #pragma unroll
  for (int tm = 0; tm < 2; ++tm) {
    const int rbase = m0 + wm*32 + tm*16 + quad*4;
    #pragma unroll
    for (int tn = 0; tn < 2; ++tn) {
      const int col = n0 + wn*32 + tn*16 + lm;
      floatx4 a4 = acc[tm][tn];
      if (MODE == 0) {
        ushort4v pk;
        #pragma unroll
        for (int r = 0; r < 4; ++r) {
          int d = rbase + r;
          float xv = X[((size_t)(b * 256 + d)) * NPIX + col];
          pk[r] = f2b(xv * rsqrtf(vec[d] + a4[r]));
        }
        *(ushort4v*)&o0[((size_t)(b * NPIX + col)) * 256 + rbase] = pk;
      } else if (MODE == 1) {
        const int part = rbase >> 8, h = (rbase >> 5) & 7, dd = rbase & 31;
        if (part == 2) {           // V transposed: [b][h][d][n]
          #pragma unroll
          for (int r = 0; r < 4; ++r)
            o2[(((size_t)(b * 8 + h)) * 32 + dd + r) * NPIX + col] = f2b(a4[r]);
        } else {
          unsigned short* dst = part == 0 ? o0 : o1;
          const float sc = (part == 0) ? (QSCALE * L2E) : 1.0f;
          ushort4v pk;
          #pragma unroll
          for (int r = 0; r < 4; ++r) pk[r] = f2b(a4[r] * sc);
          *(ushort4v*)&dst[(((size_t)(b * 8 + h)) * NPIX + col) * 32 + dd] = pk;
        }
      } else {
        #pragma unroll
        for (int r = 0; r < 4; ++r) {
          int c = rbase + r;
          of[((size_t)(b * 256 + c)) * NPIX + col] = a4[r] + vec[c];
        }
      }
    }
  }
}

// ---------------------------------------------------------------------------
// MFMA flash attention, key-split + prefetch. Block = 512 thr = 8 waves.
// Waves 0-3: keys 0..1151; waves 4-7: keys 1152..2303. Wave w handles the
// 16 queries (w&3)*16.. of the block's 64-query tile, 18 key-tiles of 64.
// K/V fragments for tile t+1 prefetched while computing tile t. Two partials
// merged in-block through an LDS overlay of the P buffer.
// ---------------------------------------------------------------------------
__global__ __launch_bounds__(512, 4) void attn_k(
    const unsigned short* __restrict__ qg, const unsigned short* __restrict__ kg,
    const unsigned short* __restrict__ vt, const float* __restrict__ tabf_g,
    unsigned short* __restrict__ ob)
{
  __shared__ __align__(16) float tabf[TBLP];             // 36.1 KB fp32 bias (x L2E)
  __shared__ __align__(16) unsigned short Pl[8][16][72]; // 18.4 KB, per-wave P
  __shared__ float lpart[2][4][16];

  const int tid = threadIdx.x;
  const int w = tid >> 6, lane = tid & 63;
  const int lm = lane & 15, quad = lane >> 4;
  const int gq = w & 3, half = w >> 2;
  const int q0 = blockIdx.x * 64;
  const int bh = blockIdx.y;
  const size_t base = (size_t)bh * NPIX * 32;
  const int j00 = half * 1152;

  { // stage per-head fp32 bias slice
    const float* src = tabf_g + (size_t)(bh & 7) * TBLP;
    for (int e = tid * 4; e < TBLP; e += 2048)
      *(float4*)&tabf[e] = *(const float4*)&src[e];
  }
  __syncthreads();

  // Q fragment: B-operand for S^T (n=lm=q, k=quad*8+j=d); pre-scaled QSCALE*L2E
  const int q = q0 + gq * 16 + lm;
  const short8 qfrag = *(const short8*)&qg[base + (size_t)q * 32 + quad * 8];

  // bias row base for this lane's query
  const int hi = (q * 43691) >> 21;                  // q / 48
  const int rb = (hi + 47) * 95 + (q - hi * 48) + 47;

  float lsum = 0.f;
  floatx4 o[2] = {};

  // prefetch registers: K frags (A-op, key rows) and V^T frags (A-op, d rows)
  short8 kf[4], vf[4];
  #pragma unroll
  for (int kt = 0; kt < 4; ++kt)
    kf[kt] = *(const short8*)&kg[base + (size_t)(j00 + kt * 16 + lm) * 32 + quad * 8];
  #pragma unroll
  for (int c = 0; c < 2; ++c)
    #pragma unroll
    for (int dt = 0; dt < 2; ++dt)
      vf[c * 2 + dt] = *(const short8*)&vt[base + (size_t)(dt * 16 + lm) * NPIX + j00 + c * 32 + quad * 8];

  for (int t = 0; t < 18; ++t) {
    const int j0 = j00 + t * 64;
    const int j0n = j00 + (t < 17 ? t + 1 : t) * 64;   // clamped prefetch target
    short8 kn[4], vn[4];
    #pragma unroll
    for (int kt = 0; kt < 4; ++kt)
      kn[kt] = *(const short8*)&kg[base + (size_t)(j0n + kt * 16 + lm) * 32 + quad * 8];
    #pragma unroll
    for (int c = 0; c < 2; ++c)
      #pragma unroll
      for (int dt = 0; dt < 2; ++dt)
        vn[c * 2 + dt] = *(const short8*)&vt[base + (size_t)(dt * 16 + lm) * NPIX + j0n + c * 32 + quad * 8];

    // S^T[key][q]: rows = keys (quad*4+r per kt), cols = queries (lm)
    floatx4 s4[4];
    #pragma unroll
    for (int kt = 0; kt < 4; ++kt) {
      floatx4 z = {};
      s4[kt] = __builtin_amdgcn_mfma_f32_16x16x32_bf16(kf[kt], qfrag, z, 0, 0, 0);
    }
    // + bias, exp2, accumulate l, pack P
    #pragma unroll
    for (int kt = 0; kt < 4; ++kt) {
      const int key0 = j0 + kt * 16 + quad * 4;      // 4-aligned: same 48-row for r=0..3
      const int hj = (key0 * 43691) >> 21;           // key0 / 48
      const int ib = rb - key0 - hj * 47;            // bias idx for r=0, decreasing in r
      ushort4v pk;
      #pragma unroll
      for (int r = 0; r < 4; ++r) {
        float p = __builtin_amdgcn_exp2f(s4[kt][r] + tabf[ib - r]);
        lsum += p;
        pk[r] = f2b_fast(p);
      }
      *(ushort4v*)&Pl[w][lm][kt * 16 + quad * 4] = pk;   // P[q][key] layout
    }
    __asm__ volatile("s_waitcnt lgkmcnt(0)" ::: "memory"); // wave-local DS order
    // O^T[d][q] += V^T[d][key] * P^T[key][q]
    #pragma unroll
    for (int c = 0; c < 2; ++c) {
      short8 pf = *(const short8*)&Pl[w][lm][c * 32 + quad * 8];
      #pragma unroll
      for (int dt = 0; dt < 2; ++dt)
        o[dt] = __builtin_amdgcn_mfma_f32_16x16x32_bf16(vf[c * 2 + dt], pf, o[dt], 0, 0, 0);
    }
    #pragma unroll
    for (int i2 = 0; i2 < 4; ++i2) { kf[i2] = kn[i2]; vf[i2] = vn[i2]; }
  }

  // reduce l across the 4 quads holding the same query
  lsum += __shfl_xor(lsum, 16, 64);
  lsum += __shfl_xor(lsum, 32, 64);

  // write partials to LDS overlay of Pl: Om[half][gq][q=16][36]
  float* Om = (float*)&Pl[0][0][0];
  {
    const int rowb = ((half * 4 + gq) * 16 + lm) * 36;
    #pragma unroll
    for (int dt = 0; dt < 2; ++dt)
      *(floatx4*)&Om[rowb + dt * 16 + quad * 4] = o[dt];
    if (quad == 0) lpart[half][gq][lm] = lsum;
  }
  __syncthreads();

  // merge: waves 0-3 combine the two key-half partials for their query group
  if (w < 4) {
    const int qq = lane >> 2, dg = lane & 3;
    const float inv = 1.f / (lpart[0][w][qq] + lpart[1][w][qq]);
    const float* r0 = &Om[((0 * 4 + w) * 16 + qq) * 36 + dg * 8];
    const float* r1 = &Om[((1 * 4 + w) * 16 + qq) * 36 + dg * 8];
    short8 pk;
    #pragma unroll
    for (int r = 0; r < 8; ++r)
      pk[r] = (short)f2b((r0[r] + r1[r]) * inv);
    *(short8*)&ob[base + (size_t)(q0 + w * 16 + qq) * 32 + dg * 8] = pk;
  }
}

// ---------------------------------------------------------------------------
extern "C" void kernel_launch(void* const* d_in, const int* in_sizes, int n_in,
                              void* d_out, int out_size, void* d_ws, size_t ws_size,
                              hipStream_t stream) {
  const float* x     = (const float*)d_in[0];
  const float* beta  = (const float*)d_in[1];
  const float* gamma = (const float*)d_in[2];
  const float* wqkv  = (const float*)d_in[3];
  const float* wout  = (const float*)d_in[4];
  const float* bout  = (const float*)d_in[5];
  const float* table = (const float*)d_in[6];
  float* out = (float*)d_out;   // reference output dtype is float32

  unsigned short* ws = (unsigned short*)d_ws;
  const size_t NE = (size_t)NB * NPIX * 256;   // 1,179,648 elems per tensor
  unsigned short* xn_t  = ws;                  // [b][n][256] bf16
  unsigned short* qbuf  = ws + NE;             // [b][h][n][32] bf16, *QSCALE*L2E
  unsigned short* kbuf  = ws + 2 * NE;         // [b][h][n][32]
  unsigned short* vtbuf = ws + 3 * NE;         // [b][h][32][n]  (transposed)
  unsigned short* obuf  = ws + 4 * NE;         // [b][h][n][32] == res[b][n2][e]
  // bf16 weights: gamma/wqkv alias obuf (dead before attn writes it)
  unsigned short* gam_b = obuf;                // 65536
  unsigned short* qkv_b = obuf + 65536;        // 196608 (fits in NE)
  unsigned short* out_b = ws + 5 * NE;         // 65536 (live through gemm2)
  float* tab_f = (float*)(ws + 5 * NE + 65536); // 8*TBLP fp32 (live through attn)

  prep_k<<<768, 256, 0, stream>>>(gamma, wqkv, wout, table, gam_b, qkv_b, out_b, tab_f);
  gemm_k<0><<<dim3(36, 4, 2), 256, 0, stream>>>(gam_b, x, beta, xn_t, nullptr, nullptr, nullptr);
  gemm_k<1><<<dim3(36, 12, 2), 256, 0, stream>>>(qkv_b, xn_t, nullptr, qbuf, kbuf, vtbuf, nullptr);
  attn_k<<<dim3(36, 16), 512, 0, stream>>>(qbuf, kbuf, vtbuf, tab_f, obuf);
  gemm_k<2><<<dim3(36, 4, 2), 256, 0, stream>>>(out_b, obuf, bout, nullptr, nullptr, nullptr, out);
}